// Round 8
// baseline (285.746 us; speedup 1.0000x reference)
//
#include <hip/hip_runtime.h>
#include <math.h>

#define B_  4
#define S_  2048
#define D_  1024
#define H_  16
#define HD_ 64
#define M_  (B_*S_)   // 8192

typedef short short8 __attribute__((ext_vector_type(8)));
typedef float f32x4 __attribute__((ext_vector_type(4)));

#define MFMA16(a,b,c) __builtin_amdgcn_mfma_f32_16x16x32_bf16(a, b, c, 0, 0, 0)

#if __has_builtin(__builtin_amdgcn_exp2f)
#define EXP2(x) __builtin_amdgcn_exp2f(x)
#else
#define EXP2(x) exp2f(x)
#endif

__device__ __forceinline__ unsigned short f2bf(float f) {
    unsigned u = __float_as_uint(f);
    u = (u + 0x7FFF + ((u >> 16) & 1)) >> 16;
    return (unsigned short)u;
}

// pack two fp32 -> two bf16 in one u32 (RNE)
__device__ __forceinline__ unsigned pack_bf16(float a, float b) {
#if __has_builtin(__builtin_amdgcn_cvt_pk_bf16_f32)
    typedef __bf16 bf2 __attribute__((ext_vector_type(2)));
    bf2 v = __builtin_amdgcn_cvt_pk_bf16_f32(a, b);
    unsigned r;
    __builtin_memcpy(&r, &v, 4);
    return r;
#else
    unsigned ua = __float_as_uint(a), ub = __float_as_uint(b);
    ua += 0x7FFFu + ((ua >> 16) & 1u);
    ub += 0x7FFFu + ((ub >> 16) & 1u);
    return __builtin_amdgcn_perm(ub, ua, 0x07060302u);
#endif
}

__device__ __forceinline__ void async_copy16(const void* g, void* l) {
    __builtin_amdgcn_global_load_lds(
        (const __attribute__((address_space(1))) void*)g,
        (__attribute__((address_space(3))) void*)l, 16, 0, 0);
}

#define VMW(n) asm volatile("s_waitcnt vmcnt(" #n ")" ::: "memory")
#define BARS() do { __builtin_amdgcn_s_barrier(); \
                    __builtin_amdgcn_sched_barrier(0); } while (0)

// ---------------- fused fp32->bf16 conversion (x + 4 weights) ----------------
__global__ __launch_bounds__(256) void cvt_all(
    const float* __restrict__ x,
    const float* __restrict__ w0, const float* __restrict__ w1,
    const float* __restrict__ w2, const float* __restrict__ w3,
    unsigned short* __restrict__ xb, unsigned short* __restrict__ wb)
{
    size_t i = ((size_t)blockIdx.x * 256 + threadIdx.x) * 4;
    const float* src; unsigned short* dst;
    if (i < (size_t)M_ * D_) {
        src = x + i; dst = xb + i;
    } else {
        size_t j = i - (size_t)M_ * D_;
        int z = (int)(j >> 20);               // D_*D_ = 2^20
        const float* w = (z == 0) ? w0 : (z == 1) ? w1 : (z == 2) ? w2 : w3;
        src = w + (j & ((size_t)D_ * D_ - 1)); dst = wb + j;
    }
    float4 v = *(const float4*)src;
    uint2 o;
    o.x = pack_bf16(v.x, v.y);
    o.y = pack_bf16(v.z, v.w);
    *(uint2*)dst = o;
}

// ---------------- fused QKV GEMM: 256x256, 4-phase, counted vmcnt ----------
__global__ __launch_bounds__(512, 2) void qkv256(
    const unsigned short* __restrict__ A,   // xb [8192][1024]
    const unsigned short* __restrict__ W,   // wb [3072][1024] (q|k|v)
    const float* __restrict__ bq, const float* __restrict__ bk,
    const float* __restrict__ bv,
    unsigned short* __restrict__ Qo, unsigned short* __restrict__ Ko,
    unsigned short* __restrict__ Vo)
{
    __shared__ unsigned short As[2][256 * 64];
    __shared__ unsigned short Ws[2][256 * 64];
    const int K = D_;
    int tid = threadIdx.x;
    int w = tid >> 6, lane = tid & 63;
    int quad = lane >> 4, l16 = lane & 15;
    int r8 = lane >> 3, c8 = lane & 7;
    int cK = c8 ^ r8;                   // staging: LDS[r][c] = src[r][c^(r&7)]
    int wm = w >> 2, wn = w & 3;        // 2 x 4 wave grid
    int fl = l16 & 7;

    int lin = blockIdx.x + 12 * blockIdx.y;
    int swz = (lin & 7) * 48 + (lin >> 3);
    int by = swz / 12, bx = swz % 12;
    int m0 = by * 256, n0 = bx * 256;

    int z = bx >> 2;                    // 0:Q 1:K 2:V
    const float* bias = (z == 0) ? bq : (z == 1) ? bk : bv;
    unsigned short* out = (z == 0) ? Qo : (z == 1) ? Ko : Vo;
    float cscale = (z == 0) ? 0.125f * 1.44269504088896f : 1.0f;

    f32x4 acc[8][4];
    #pragma unroll
    for (int i = 0; i < 8; ++i)
        #pragma unroll
        for (int j = 0; j < 4; ++j)
            acc[i][j] = (f32x4){0.f, 0.f, 0.f, 0.f};

    const unsigned short* Ag = A + (size_t)(m0 + r8) * K + cK * 8;
    const unsigned short* Wg = W + (size_t)(n0 + r8) * K + cK * 8;

    auto stA = [&](int slot, int kt, int h) {
        #pragma unroll
        for (int ii = 0; ii < 2; ++ii) {
            int rb = ii * 128 + h * 64 + w * 8;
            async_copy16(Ag + (size_t)rb * K + kt * 64, &As[slot][rb * 64]);
        }
    };
    auto stB = [&](int slot, int kt, int h) {
        #pragma unroll
        for (int ii = 0; ii < 2; ++ii) {
            int rb = (ii * 2 + (w >> 2)) * 64 + h * 32 + (w & 3) * 8;
            async_copy16(Wg + (size_t)rb * K + kt * 64, &Ws[slot][rb * 64]);
        }
    };

    stA(0, 0, 0); stB(0, 0, 0); stB(0, 0, 1); stA(0, 0, 1);
    VMW(4);
    BARS();

    #define RD_A(i, off, s) (*(const short8*)&As[cur][(wm * 128 + (off) + (i) * 16 + l16) * 64 + \
                              (((quad + (s) * 4) ^ fl) * 8)])
    #define RD_B(j, off, s) (*(const short8*)&Ws[cur][(wn * 64 + (off) + (j) * 16 + l16) * 64 + \
                              (((quad + (s) * 4) ^ fl) * 8)])

    const int NT = K / 64;  // 16
    for (int kt = 0; kt < NT; ++kt) {
        int cur = kt & 1, nxt = cur ^ 1;
        bool pre = (kt + 1 < NT);
        short8 a[4][2], b0[2][2], b1[2][2];

        // ---- P1
        #pragma unroll
        for (int i = 0; i < 4; ++i)
            #pragma unroll
            for (int s = 0; s < 2; ++s) a[i][s] = RD_A(i, 0, s);
        #pragma unroll
        for (int j = 0; j < 2; ++j)
            #pragma unroll
            for (int s = 0; s < 2; ++s) b0[j][s] = RD_B(j, 0, s);
        if (pre) { stA(nxt, kt + 1, 0); VMW(4); } else VMW(2);
        BARS();
        #pragma unroll
        for (int i = 0; i < 4; ++i)
            #pragma unroll
            for (int j = 0; j < 2; ++j)
                #pragma unroll
                for (int s = 0; s < 2; ++s)
                    acc[i][j] = MFMA16(a[i][s], b0[j][s], acc[i][j]);

        // ---- P2
        #pragma unroll
        for (int j = 0; j < 2; ++j)
            #pragma unroll
            for (int s = 0; s < 2; ++s) b1[j][s] = RD_B(j, 32, s);
        if (pre) { stB(nxt, kt + 1, 0); VMW(4); } else VMW(0);
        BARS();
        #pragma unroll
        for (int i = 0; i < 4; ++i)
            #pragma unroll
            for (int j = 0; j < 2; ++j)
                #pragma unroll
                for (int s = 0; s < 2; ++s)
                    acc[i][j + 2] = MFMA16(a[i][s], b1[j][s], acc[i][j + 2]);

        // ---- P3
        #pragma unroll
        for (int i = 0; i < 4; ++i)
            #pragma unroll
            for (int s = 0; s < 2; ++s) a[i][s] = RD_A(i, 64, s);
        if (pre) stB(nxt, kt + 1, 1);
        BARS();
        #pragma unroll
        for (int i = 0; i < 4; ++i)
            #pragma unroll
            for (int j = 0; j < 2; ++j)
                #pragma unroll
                for (int s = 0; s < 2; ++s)
                    acc[i + 4][j + 2] = MFMA16(a[i][s], b1[j][s], acc[i + 4][j + 2]);

        // ---- P4
        if (pre) { stA(nxt, kt + 1, 1); VMW(4); }
        BARS();
        #pragma unroll
        for (int i = 0; i < 4; ++i)
            #pragma unroll
            for (int j = 0; j < 2; ++j)
                #pragma unroll
                for (int s = 0; s < 2; ++s)
                    acc[i + 4][j] = MFMA16(a[i][s], b0[j][s], acc[i + 4][j]);
    }
    #undef RD_A
    #undef RD_B

    #pragma unroll
    for (int ih = 0; ih < 2; ++ih)
    #pragma unroll
    for (int i = 0; i < 4; ++i) {
        int mb = m0 + wm * 128 + ih * 64 + i * 16 + quad * 4;
        #pragma unroll
        for (int j = 0; j < 4; ++j) {
            int n = n0 + wn * 64 + j * 16 + l16;
            int nn = n & 1023;
            float bn = bias[nn];
            int h = nn >> 6, hd = nn & 63;
            f32x4 v = acc[ih * 4 + i][j];
            if (z != 2) {
                #pragma unroll
                for (int r = 0; r < 4; ++r) {
                    int m = mb + r;
                    int bb = m >> 11, s = m & (S_ - 1);
                    out[(((size_t)(bb * H_ + h)) * S_ + s) * HD_ + hd] =
                        f2bf((v[r] + bn) * cscale);
                }
            } else {
                int bb = mb >> 11, s0 = mb & (S_ - 1);
                uint2 o;
                o.x = pack_bf16(v[0] + bn, v[1] + bn);
                o.y = pack_bf16(v[2] + bn, v[3] + bn);
                *(uint2*)&out[(((size_t)(bb * H_ + h)) * HD_ + hd) * S_ + s0] = o;
            }
        }
    }
}

// ---------------- bf16 MFMA GEMM: 128x128, dbuf LDS (out projection) --------
__device__ __forceinline__ void gemm_body(
    const unsigned short* __restrict__ A, const unsigned short* __restrict__ W,
    const float* __restrict__ bias, void* __restrict__ out,
    int mode, float cscale, int bx, int by)
{
    __shared__ unsigned short As[2][128 * 64];
    __shared__ unsigned short Ws[2][128 * 64];
    const int K = D_;
    int tid = threadIdx.x;
    int w = tid >> 6, lane = tid & 63;
    int quad = lane >> 4, l16 = lane & 15;
    int r8 = lane >> 3, c8 = lane & 7;
    int cK = c8 ^ r8;
    int wm = w >> 2, wn = w & 3;
    int m0 = by * 128, n0 = bx * 128;
    int fl = l16 & 7;

    f32x4 acc[4][2];
    #pragma unroll
    for (int i = 0; i < 4; ++i)
        #pragma unroll
        for (int j = 0; j < 2; ++j)
            acc[i][j] = (f32x4){0.f, 0.f, 0.f, 0.f};

    const unsigned short* Ag = A + (size_t)(m0 + w * 16 + r8) * K + cK * 8;
    const unsigned short* Wg = W + (size_t)(n0 + w * 16 + r8) * K + cK * 8;

    auto stage = [&](int slot, int kt) {
        #pragma unroll
        for (int ii = 0; ii < 2; ++ii) {
            async_copy16(Ag + (size_t)(ii * 8) * K + kt * 64,
                         &As[slot][(w * 16 + ii * 8) * 64]);
            async_copy16(Wg + (size_t)(ii * 8) * K + kt * 64,
                         &Ws[slot][(w * 16 + ii * 8) * 64]);
        }
    };

    stage(0, 0);
    __syncthreads();

    const int NT = K / 64;  // 16
    for (int kt = 0; kt < NT; ++kt) {
        int cur = kt & 1;
        if (kt + 1 < NT) stage(cur ^ 1, kt + 1);

        #pragma unroll
        for (int s = 0; s < 2; ++s) {
            int st = ((quad + s * 4) ^ fl) * 8;
            short8 a[4], b[2];
            #pragma unroll
            for (int i = 0; i < 4; ++i)
                a[i] = *(const short8*)&As[cur][(wm * 64 + i * 16 + l16) * 64 + st];
            #pragma unroll
            for (int j = 0; j < 2; ++j)
                b[j] = *(const short8*)&Ws[cur][(wn * 32 + j * 16 + l16) * 64 + st];
            #pragma unroll
            for (int i = 0; i < 4; ++i)
                #pragma unroll
                for (int j = 0; j < 2; ++j)
                    acc[i][j] = MFMA16(a[i], b[j], acc[i][j]);
        }

        asm volatile("s_waitcnt vmcnt(0)" ::: "memory");
        __builtin_amdgcn_s_barrier();
        __builtin_amdgcn_sched_barrier(0);
    }

    #pragma unroll
    for (int i = 0; i < 4; ++i) {
        int mb = m0 + wm * 64 + i * 16 + quad * 4;
        #pragma unroll
        for (int j = 0; j < 2; ++j) {
            int n = n0 + wn * 32 + j * 16 + l16;
            float bn = bias[n];
            if (mode == 0) {
                #pragma unroll
                for (int r = 0; r < 4; ++r)
                    ((float*)out)[(size_t)(mb + r) * D_ + n] = acc[i][j][r] + bn;
            }
        }
    }
}

__global__ __launch_bounds__(512, 4) void out_gemm(
    const unsigned short* __restrict__ A, const unsigned short* __restrict__ W,
    const float* __restrict__ bias, float* __restrict__ out)
{
    int lin = blockIdx.x + 8 * blockIdx.y;
    int swz = (lin & 7) * 64 + (lin >> 3);
    gemm_body(A, W, bias, out, 0, 1.0f, swz & 7, swz >> 3);
}

// ---------------- flash attention (R11: QBLK=128, 3 blocks/CU) -------------
// Block = 128 queries of one (b,h); 8 waves x 16 queries; 512 threads.
// LDS = QPs 16K + K 2x8K + V 2x8K = 48 KiB -> 3 blocks/CU = 24 waves/CU
// (was 80K/2blk/16 waves; Occupancy 36% said waves, not pipes, were the
// limit). K/V 2-slot: issue kt+1 at top, drain at bottom after the full
// compute phase (R6-proven). Grid (bh, 16 qblk) keeps XCD = bh%8 locality.
__global__ __launch_bounds__(512, 6) void attn_mfma(
    const unsigned short* __restrict__ Q, const unsigned short* __restrict__ K,
    const unsigned short* __restrict__ VT, unsigned short* __restrict__ ctx)
{
    __shared__ unsigned short Ks[2 * 64 * 64];    // 2-slot K tiles
    __shared__ unsigned short VTs[2 * 64 * 64];   // 2-slot V^T tiles
    __shared__ unsigned short QPs[128 * 64];      // Q staged, then P (wave-private)

    int tid = threadIdx.x;
    int w = tid >> 6, lane = tid & 63;
    int quad = lane >> 4, l16 = lane & 15;
    int r8 = lane >> 3, c8 = lane & 7;
    int cK = c8 ^ r8;                     // K/V staging swizzle f(r)=r&7
    int fl  = l16 & 7;                    // K/V read key
    int fl2 = (l16 ^ (l16 >> 1)) & 7;     // Q/P swizzle key
    int bh = blockIdx.x;                  // bh major -> XCD = bh%8 (L2 locality)
    int q0 = blockIdx.y * 128;

    const unsigned short* Qp = Q + ((size_t)bh * S_ + q0) * HD_;
    const unsigned short* Kp = K + (size_t)bh * S_ * HD_;
    const unsigned short* Vp = VT + (size_t)bh * HD_ * S_;

    // stage Q tile [128][64]; rows ii*64 + w*8 + r8 (ii=0..1)
    int cQ = c8 ^ r8 ^ (r8 >> 1) ^ ((w & 1) * 4);
    #pragma unroll
    for (int ii = 0; ii < 2; ++ii)
        async_copy16(Qp + (size_t)(ii * 64 + w * 8 + r8) * HD_ + cQ * 8,
                     QPs + (ii * 64 + w * 8) * 64);
    // stage K/V tile 0 into slot 0 (1 load each per wave: rows w*8 + r8)
    async_copy16(Kp + (size_t)(w * 8 + r8) * HD_ + cK * 8, Ks + (w * 8) * 64);
    async_copy16(Vp + (size_t)(w * 8 + r8) * S_ + cK * 8, VTs + (w * 8) * 64);
    __syncthreads();

    // Q fragments (B-operand: n=query=l16 of this wave's 16, k=quad*8+j)
    short8 bq_[2];
    #pragma unroll
    for (int s = 0; s < 2; ++s)
        bq_[s] = *(const short8*)&QPs[(w * 16 + l16) * 64 +
                                      (((quad + s * 4) ^ fl2) * 8)];

    f32x4 O[4];
    float lsum = 0.f;
    #pragma unroll
    for (int nt = 0; nt < 4; ++nt) O[nt] = (f32x4){0.f, 0.f, 0.f, 0.f};

    const int NT = S_ / 64;   // 32
    int cur = 0;
    for (int kt = 0; kt < NT; ++kt) {
        // issue tile kt+1 into the other slot; drained by the bottom barrier
        // after the full compute phase
        if (kt + 1 < NT) {
            int nb = (cur ^ 1) * 4096;
            async_copy16(Kp + (size_t)((kt + 1) * 64 + w * 8 + r8) * HD_ + cK * 8,
                         Ks + nb + (w * 8) * 64);
            async_copy16(Vp + (size_t)(w * 8 + r8) * S_ + (kt + 1) * 64 + cK * 8,
                         VTs + nb + (w * 8) * 64);
        }
        const unsigned short* ks  = Ks + cur * 4096;
        const unsigned short* vts = VTs + cur * 4096;

        // S^T = K @ Q^T: sc[nt] col=query(l16), rows=keys(quad*4+r)
        f32x4 sc[4];
        #pragma unroll
        for (int nt = 0; nt < 4; ++nt) sc[nt] = (f32x4){0.f, 0.f, 0.f, 0.f};
        #pragma unroll
        for (int s = 0; s < 2; ++s) {
            int stk = ((quad + s * 4) ^ fl) * 8;
            #pragma unroll
            for (int nt = 0; nt < 4; ++nt) {
                short8 ak = *(const short8*)&ks[(nt * 16 + l16) * 64 + stk];
                sc[nt] = MFMA16(ak, bq_[s], sc[nt]);
            }
        }

        // p = exp2(s) (Q pre-scaled by log2e/8); packed bf16x2 P-writes
        #pragma unroll
        for (int nt = 0; nt < 4; ++nt) {
            float p0 = EXP2(sc[nt][0]);
            float p1 = EXP2(sc[nt][1]);
            float p2 = EXP2(sc[nt][2]);
            float p3 = EXP2(sc[nt][3]);
            lsum += (p0 + p1) + (p2 + p3);
            uint2 pk;
            pk.x = pack_bf16(p0, p1);
            pk.y = pack_bf16(p2, p3);
            // row = query (w*16 + l16), col = key = nt*16 + quad*4 + r
            int addr = (w * 16 + l16) * 64 +
                       (((nt * 2 + (quad >> 1)) ^ fl2) * 8) + (quad & 1) * 4;
            *(uint2*)&QPs[addr] = pk;
        }

        // O += P @ V  (wave-local LDS round trip)
        #pragma unroll
        for (int s = 0; s < 2; ++s) {
            int stp = ((quad + s * 4) ^ fl2) * 8;
            int stv = ((quad + s * 4) ^ fl) * 8;
            short8 pa = *(const short8*)&QPs[(w * 16 + l16) * 64 + stp];
            #pragma unroll
            for (int nt = 0; nt < 4; ++nt) {
                short8 bv_ = *(const short8*)&vts[(nt * 16 + l16) * 64 + stv];
                O[nt] = MFMA16(pa, bv_, O[nt]);
            }
        }

        asm volatile("s_waitcnt vmcnt(0)" ::: "memory");
        __builtin_amdgcn_s_barrier();
        __builtin_amdgcn_sched_barrier(0);
        cur ^= 1;
    }

    // row sum: reduce over quad lanes (each lane holds 16 of its query's keys)
    float l = lsum;
    l += __shfl_xor(l, 16);
    l += __shfl_xor(l, 32);
    float linv = 1.0f / l;      // sum for query (w*16 + l16)

    // normalize + write: O rows are queries quad*4+r -> fetch inv via shuffle
    int b = bh >> 4, h = bh & (H_ - 1);
    #pragma unroll
    for (int r = 0; r < 4; ++r) {
        float inv = __shfl(linv, quad * 4 + r, 64);
        int q = q0 + w * 16 + quad * 4 + r;
        size_t base = ((size_t)(b * S_) + q) * D_ + h * HD_;
        #pragma unroll
        for (int nt = 0; nt < 4; ++nt)
            ctx[base + nt * 16 + l16] = f2bf(O[nt][r] * inv);
    }
}

extern "C" void kernel_launch(void* const* d_in, const int* in_sizes, int n_in,
                              void* d_out, int out_size, void* d_ws, size_t ws_size,
                              hipStream_t stream) {
    const float* x  = (const float*)d_in[0];
    const float* Wq = (const float*)d_in[1];
    const float* bq = (const float*)d_in[2];
    const float* Wk = (const float*)d_in[3];
    const float* bk = (const float*)d_in[4];
    const float* Wv = (const float*)d_in[5];
    const float* bv = (const float*)d_in[6];
    const float* Wo = (const float*)d_in[7];
    const float* bo = (const float*)d_in[8];

    unsigned short* xb  = (unsigned short*)d_ws;
    unsigned short* wb  = xb + (size_t)M_ * D_;
    unsigned short* Qb  = wb + (size_t)4 * D_ * D_;
    unsigned short* Kb  = Qb + (size_t)M_ * D_;
    unsigned short* VTb = Kb + (size_t)M_ * D_;
    unsigned short* ctb = VTb + (size_t)M_ * D_;

    int cvt_blocks = (M_ * D_ + 4 * D_ * D_) / 1024;
    cvt_all<<<cvt_blocks, 256, 0, stream>>>(x, Wq, Wk, Wv, Wo, xb, wb);

    qkv256<<<dim3(12, 32), 512, 0, stream>>>(
        xb, wb, bq, bk, bv, Qb, Kb, VTb);

    attn_mfma<<<dim3(B_ * H_, S_ / 128), 512, 0, stream>>>(Qb, Kb, VTb, ctb);

    out_gemm<<<dim3(D_ / 128, M_ / 128), 512, 0, stream>>>(
        ctb, wb + (size_t)3 * D_ * D_, bo, (float*)d_out);
}

// Round 9
// 267.051 us; speedup vs baseline: 1.0700x; 1.0700x over previous
//
#include <hip/hip_runtime.h>
#include <math.h>

#define B_  4
#define S_  2048
#define D_  1024
#define H_  16
#define HD_ 64
#define M_  (B_*S_)   // 8192

typedef short short8 __attribute__((ext_vector_type(8)));
typedef float f32x4 __attribute__((ext_vector_type(4)));

#define MFMA16(a,b,c) __builtin_amdgcn_mfma_f32_16x16x32_bf16(a, b, c, 0, 0, 0)

#if __has_builtin(__builtin_amdgcn_exp2f)
#define EXP2(x) __builtin_amdgcn_exp2f(x)
#else
#define EXP2(x) exp2f(x)
#endif

__device__ __forceinline__ unsigned short f2bf(float f) {
    unsigned u = __float_as_uint(f);
    u = (u + 0x7FFF + ((u >> 16) & 1)) >> 16;
    return (unsigned short)u;
}

// pack two fp32 -> two bf16 in one u32 (RNE)
__device__ __forceinline__ unsigned pack_bf16(float a, float b) {
#if __has_builtin(__builtin_amdgcn_cvt_pk_bf16_f32)
    typedef __bf16 bf2 __attribute__((ext_vector_type(2)));
    bf2 v = __builtin_amdgcn_cvt_pk_bf16_f32(a, b);
    unsigned r;
    __builtin_memcpy(&r, &v, 4);
    return r;
#else
    unsigned ua = __float_as_uint(a), ub = __float_as_uint(b);
    ua += 0x7FFFu + ((ua >> 16) & 1u);
    ub += 0x7FFFu + ((ub >> 16) & 1u);
    return __builtin_amdgcn_perm(ub, ua, 0x07060302u);
#endif
}

__device__ __forceinline__ void async_copy16(const void* g, void* l) {
    __builtin_amdgcn_global_load_lds(
        (const __attribute__((address_space(1))) void*)g,
        (__attribute__((address_space(3))) void*)l, 16, 0, 0);
}

// ---------------- fused fp32->bf16 conversion (x + 4 weights) ----------------
__global__ __launch_bounds__(256) void cvt_all(
    const float* __restrict__ x,
    const float* __restrict__ w0, const float* __restrict__ w1,
    const float* __restrict__ w2, const float* __restrict__ w3,
    unsigned short* __restrict__ xb, unsigned short* __restrict__ wb)
{
    size_t i = ((size_t)blockIdx.x * 256 + threadIdx.x) * 4;
    const float* src; unsigned short* dst;
    if (i < (size_t)M_ * D_) {
        src = x + i; dst = xb + i;
    } else {
        size_t j = i - (size_t)M_ * D_;
        int z = (int)(j >> 20);               // D_*D_ = 2^20
        const float* w = (z == 0) ? w0 : (z == 1) ? w1 : (z == 2) ? w2 : w3;
        src = w + (j & ((size_t)D_ * D_ - 1)); dst = wb + j;
    }
    float4 v = *(const float4*)src;
    uint2 o;
    o.x = pack_bf16(v.x, v.y);
    o.y = pack_bf16(v.z, v.w);
    *(uint2*)dst = o;
}

// ---------------- bf16 MFMA GEMM: 128x128, dbuf LDS, issue-early ------------
// 512 threads, 8 waves as 2x4. LDS = 2 slots x (As+Ws 16KB each) = 64 KiB ->
// 2 blocks/CU. Per iter: issue next K-tile's global_load_lds at TOP, compute
// current slot, then ONE aged vmcnt(0) + raw s_barrier at the bottom.
__device__ __forceinline__ void gemm_body(
    const unsigned short* __restrict__ A, const unsigned short* __restrict__ W,
    const float* __restrict__ bias, void* __restrict__ out,
    int mode, float cscale, int bx, int by)
{
    __shared__ unsigned short As[2][128 * 64];
    __shared__ unsigned short Ws[2][128 * 64];
    const int K = D_;
    int tid = threadIdx.x;
    int w = tid >> 6, lane = tid & 63;
    int quad = lane >> 4, l16 = lane & 15;
    int r8 = lane >> 3, c8 = lane & 7;
    int cK = c8 ^ r8;                       // staging swizzle: LDS[r][c]=src[r][c^(r&7)]
    int wm = w >> 2, wn = w & 3;
    int m0 = by * 128, n0 = bx * 128;
    int fl = l16 & 7;

    f32x4 acc[4][2];
    #pragma unroll
    for (int i = 0; i < 4; ++i)
        #pragma unroll
        for (int j = 0; j < 2; ++j)
            acc[i][j] = (f32x4){0.f, 0.f, 0.f, 0.f};

    const unsigned short* Ag = A + (size_t)(m0 + w * 16 + r8) * K + cK * 8;
    const unsigned short* Wg = W + (size_t)(n0 + w * 16 + r8) * K + cK * 8;

    auto stage = [&](int slot, int kt) {
        #pragma unroll
        for (int ii = 0; ii < 2; ++ii) {
            async_copy16(Ag + (size_t)(ii * 8) * K + kt * 64,
                         &As[slot][(w * 16 + ii * 8) * 64]);
            async_copy16(Wg + (size_t)(ii * 8) * K + kt * 64,
                         &Ws[slot][(w * 16 + ii * 8) * 64]);
        }
    };

    stage(0, 0);
    __syncthreads();

    const int NT = K / 64;  // 16
    for (int kt = 0; kt < NT; ++kt) {
        int cur = kt & 1;
        if (kt + 1 < NT) stage(cur ^ 1, kt + 1);

        #pragma unroll
        for (int s = 0; s < 2; ++s) {
            int st = ((quad + s * 4) ^ fl) * 8;
            short8 a[4], b[2];
            #pragma unroll
            for (int i = 0; i < 4; ++i)
                a[i] = *(const short8*)&As[cur][(wm * 64 + i * 16 + l16) * 64 + st];
            #pragma unroll
            for (int j = 0; j < 2; ++j)
                b[j] = *(const short8*)&Ws[cur][(wn * 32 + j * 16 + l16) * 64 + st];
            #pragma unroll
            for (int i = 0; i < 4; ++i)
                #pragma unroll
                for (int j = 0; j < 2; ++j)
                    acc[i][j] = MFMA16(a[i], b[j], acc[i][j]);
        }

        asm volatile("s_waitcnt vmcnt(0)" ::: "memory");
        __builtin_amdgcn_s_barrier();
        __builtin_amdgcn_sched_barrier(0);
    }

    #pragma unroll
    for (int i = 0; i < 4; ++i) {
        int mb = m0 + wm * 64 + i * 16 + quad * 4;
        #pragma unroll
        for (int j = 0; j < 2; ++j) {
            int n = n0 + wn * 32 + j * 16 + l16;
            float bn = bias[n];
            if (mode == 0) {
                #pragma unroll
                for (int r = 0; r < 4; ++r)
                    ((float*)out)[(size_t)(mb + r) * D_ + n] = acc[i][j][r] + bn;
            } else if (mode == 1) {
                int h = n >> 6, hd = n & 63;
                #pragma unroll
                for (int r = 0; r < 4; ++r) {
                    int m = mb + r;
                    int bb = m >> 11, s = m & (S_ - 1);
                    ((unsigned short*)out)[(((size_t)(bb * H_ + h)) * S_ + s) * HD_ + hd] =
                        f2bf((acc[i][j][r] + bn) * cscale);
                }
            } else {
                int h = n >> 6, hd = n & 63;
                int bb = mb >> 11, s0 = mb & (S_ - 1);
                uint2 o;
                o.x = pack_bf16(acc[i][j][0] + bn, acc[i][j][1] + bn);
                o.y = pack_bf16(acc[i][j][2] + bn, acc[i][j][3] + bn);
                *(uint2*)&((unsigned short*)out)[(((size_t)(bb * H_ + h)) * HD_ + hd) * S_ + s0] = o;
            }
        }
    }
}

// fused QKV: grid (24, 64) = 1536 blocks = exactly 3 cohorts at 2 blocks/CU.
// XCD-bijective swizzle: hw lin = bx + 24*by, XCD = lin%8; each XCD gets 192
// contiguous swz ids (8 m-panels x 24 n-panels, n fastest -> A-panel hot in
// its L2, W streams from L3).
__global__ __launch_bounds__(512, 4) void qkv_gemm(
    const unsigned short* __restrict__ A, const unsigned short* __restrict__ W,
    const float* __restrict__ bq, const float* __restrict__ bk,
    const float* __restrict__ bv,
    unsigned short* __restrict__ Qo, unsigned short* __restrict__ Ko,
    unsigned short* __restrict__ Vo)
{
    int lin = blockIdx.x + 24 * blockIdx.y;
    int swz = (lin & 7) * 192 + (lin >> 3);
    int by = swz / 24, bx = swz % 24;
    int z = bx >> 3, bxl = bx & 7;
    const float* bias = (z == 0) ? bq : (z == 1) ? bk : bv;
    unsigned short* out = (z == 0) ? Qo : (z == 1) ? Ko : Vo;
    // Q pre-scaled by 1/sqrt(64) * log2(e) so softmax uses exp2 directly
    float cscale = (z == 0) ? 0.125f * 1.44269504088896f : 1.0f;
    int mode = (z == 2) ? 2 : 1;
    gemm_body(A, W + (size_t)z * D_ * D_, bias, out, mode, cscale, bxl, by);
}

__global__ __launch_bounds__(512, 4) void out_gemm(
    const unsigned short* __restrict__ A, const unsigned short* __restrict__ W,
    const float* __restrict__ bias, float* __restrict__ out)
{
    // grid (8,64) = 512 blocks = ONE full cohort at 2/CU. XCD swizzle: each
    // XCD gets 64 contiguous ids = 8 m-panels x 8 n-panels.
    int lin = blockIdx.x + 8 * blockIdx.y;
    int swz = (lin & 7) * 64 + (lin >> 3);
    gemm_body(A, W, bias, out, 0, 1.0f, swz & 7, swz >> 3);
}

// ---------------- flash attention (best: 3-slot K/V, counted vmcnt) --------
// Block = 256 queries of one (b,h); 8 waves x 32 queries; 512 threads.
// K/V triple-buffered: tile kt+2 issued at top of iter kt; bottom-of-iter
// wait is vmcnt(2) (only tile kt+1 must land; kt+2's 2 loads stay in flight
// across the raw s_barrier). LDS 80 KiB -> 2 blocks/CU. No setprio (R7 A/B:
// -4.5% on this lockstep structure). QBLK=128 (R11) was WORSE: +48% FETCH
// from redundant K/V staging across doubled q-blocks despite 50% occupancy.
// Grid is (bh, qblock): XCD = bh%8 for all q-blocks -> K/V L2-local.
__global__ __launch_bounds__(512, 4) void attn_mfma(
    const unsigned short* __restrict__ Q, const unsigned short* __restrict__ K,
    const unsigned short* __restrict__ VT, unsigned short* __restrict__ ctx)
{
    __shared__ unsigned short Ks[3 * 64 * 64];    // 3-slot K tiles
    __shared__ unsigned short VTs[3 * 64 * 64];   // 3-slot V^T tiles
    __shared__ unsigned short QPs[256 * 64];      // Q staged, then P (wave-private)

    int tid = threadIdx.x;
    int w = tid >> 6, lane = tid & 63;
    int quad = lane >> 4, l16 = lane & 15;
    int r8 = lane >> 3, c8 = lane & 7;
    int cK = c8 ^ r8;                     // K/V staging swizzle f(r)=r&7
    int fl  = l16 & 7;                    // K/V read key
    int fl2 = (l16 ^ (l16 >> 1)) & 7;     // Q/P swizzle key
    int bh = blockIdx.x;                  // bh major -> XCD = bh%8 (L2 locality)
    int q0 = blockIdx.y * 256;

    const unsigned short* Qp = Q + ((size_t)bh * S_ + q0) * HD_;
    const unsigned short* Kp = K + (size_t)bh * S_ * HD_;
    const unsigned short* Vp = VT + (size_t)bh * HD_ * S_;

    // stage Q tile [256][64]; row = ii*64 + w*8 + r8 -> l16 = (w&1)*8 + r8
    int cQ = c8 ^ r8 ^ (r8 >> 1) ^ ((w & 1) * 4);
    #pragma unroll
    for (int ii = 0; ii < 4; ++ii)
        async_copy16(Qp + (size_t)(ii * 64 + w * 8 + r8) * HD_ + cQ * 8,
                     QPs + (ii * 64 + w * 8) * 64);
    // stage K/V tiles 0 and 1 into slots 0 and 1
    #pragma unroll
    for (int t = 0; t < 2; ++t) {
        async_copy16(Kp + (size_t)(t * 64 + w * 8 + r8) * HD_ + cK * 8,
                     Ks + t * 4096 + (w * 8) * 64);
        async_copy16(Vp + (size_t)(w * 8 + r8) * S_ + t * 64 + cK * 8,
                     VTs + t * 4096 + (w * 8) * 64);
    }
    __syncthreads();

    // Q fragments (B-operand: n=query=l16, k=quad*8+j)
    short8 bq_[2][2];
    #pragma unroll
    for (int mt = 0; mt < 2; ++mt)
        #pragma unroll
        for (int s = 0; s < 2; ++s)
            bq_[mt][s] = *(const short8*)&QPs[(w * 32 + mt * 16 + l16) * 64 +
                                              (((quad + s * 4) ^ fl2) * 8)];

    f32x4 O[2][4];
    float lsum[2] = {0.f, 0.f};
    #pragma unroll
    for (int mt = 0; mt < 2; ++mt)
        #pragma unroll
        for (int nt = 0; nt < 4; ++nt) O[mt][nt] = (f32x4){0.f, 0.f, 0.f, 0.f};

    const int NT = S_ / 64;
    for (int kt = 0; kt < NT; ++kt) {
        // issue tile kt+2 into slot (kt+2)%3 (2 loads/wave; they stay in
        // flight across this iter's barrier — only kt+1 must land below)
        if (kt + 2 < NT) {
            int nb = ((kt + 2) % 3) * 4096;
            async_copy16(Kp + (size_t)((kt + 2) * 64 + w * 8 + r8) * HD_ + cK * 8,
                         Ks + nb + (w * 8) * 64);
            async_copy16(Vp + (size_t)(w * 8 + r8) * S_ + (kt + 2) * 64 + cK * 8,
                         VTs + nb + (w * 8) * 64);
        }
        const unsigned short* ks  = Ks + (kt % 3) * 4096;
        const unsigned short* vts = VTs + (kt % 3) * 4096;

        // S^T = K @ Q^T: sc[mt][nt] has col=query(l16), rows=keys(quad*4+r)
        f32x4 sc[2][4];
        #pragma unroll
        for (int mt = 0; mt < 2; ++mt)
            #pragma unroll
            for (int nt = 0; nt < 4; ++nt) sc[mt][nt] = (f32x4){0.f, 0.f, 0.f, 0.f};
        #pragma unroll
        for (int s = 0; s < 2; ++s) {
            int stk = ((quad + s * 4) ^ fl) * 8;
            #pragma unroll
            for (int nt = 0; nt < 4; ++nt) {
                short8 ak = *(const short8*)&ks[(nt * 16 + l16) * 64 + stk];
                sc[0][nt] = MFMA16(ak, bq_[0][s], sc[0][nt]);
                sc[1][nt] = MFMA16(ak, bq_[1][s], sc[1][nt]);
            }
        }

        // p = exp2(s) (Q pre-scaled by log2e/8); packed bf16x2 P-writes
        #pragma unroll
        for (int mt = 0; mt < 2; ++mt) {
            #pragma unroll
            for (int nt = 0; nt < 4; ++nt) {
                float p0 = EXP2(sc[mt][nt][0]);
                float p1 = EXP2(sc[mt][nt][1]);
                float p2 = EXP2(sc[mt][nt][2]);
                float p3 = EXP2(sc[mt][nt][3]);
                lsum[mt] += (p0 + p1) + (p2 + p3);
                uint2 pk;
                pk.x = pack_bf16(p0, p1);
                pk.y = pack_bf16(p2, p3);
                int addr = (w * 32 + mt * 16 + l16) * 64 +
                           (((nt * 2 + (quad >> 1)) ^ fl2) * 8) + (quad & 1) * 4;
                *(uint2*)&QPs[addr] = pk;
            }
        }

        // O += P @ V  (wave-local LDS round trip)
        #pragma unroll
        for (int s = 0; s < 2; ++s) {
            int stp = ((quad + s * 4) ^ fl2) * 8;
            int stv = ((quad + s * 4) ^ fl) * 8;
            short8 pa0 = *(const short8*)&QPs[(w * 32 + l16) * 64 + stp];
            short8 pa1 = *(const short8*)&QPs[(w * 32 + 16 + l16) * 64 + stp];
            #pragma unroll
            for (int nt = 0; nt < 4; ++nt) {
                short8 bv_ = *(const short8*)&vts[(nt * 16 + l16) * 64 + stv];
                O[0][nt] = MFMA16(pa0, bv_, O[0][nt]);
                O[1][nt] = MFMA16(pa1, bv_, O[1][nt]);
            }
        }

        // counted wait: tile kt+1's loads (issued last iter) must be done;
        // tile kt+2's 2 loads may stay outstanding across the barrier.
        if (kt + 2 < NT) asm volatile("s_waitcnt vmcnt(2)" ::: "memory");
        else             asm volatile("s_waitcnt vmcnt(0)" ::: "memory");
        __builtin_amdgcn_s_barrier();
        __builtin_amdgcn_sched_barrier(0);
    }

    // row sums: reduce over quad lanes (each lane holds 16 of its query's keys)
    float linv[2];
    #pragma unroll
    for (int mt = 0; mt < 2; ++mt) {
        float l = lsum[mt];
        l += __shfl_xor(l, 16);
        l += __shfl_xor(l, 32);
        linv[mt] = 1.0f / l;      // sum for query (w*32 + mt*16 + l16)
    }

    // normalize + write: O rows are queries quad*4+r -> fetch inv via shuffle
    int b = bh >> 4, h = bh & (H_ - 1);
    #pragma unroll
    for (int mt = 0; mt < 2; ++mt)
        #pragma unroll
        for (int r = 0; r < 4; ++r) {
            float inv = __shfl(linv[mt], quad * 4 + r, 64);
            int q = q0 + w * 32 + mt * 16 + quad * 4 + r;
            size_t base = ((size_t)(b * S_) + q) * D_ + h * HD_;
            #pragma unroll
            for (int nt = 0; nt < 4; ++nt)
                ctx[base + nt * 16 + l16] = f2bf(O[mt][nt][r] * inv);
        }
}

extern "C" void kernel_launch(void* const* d_in, const int* in_sizes, int n_in,
                              void* d_out, int out_size, void* d_ws, size_t ws_size,
                              hipStream_t stream) {
    const float* x  = (const float*)d_in[0];
    const float* Wq = (const float*)d_in[1];
    const float* bq = (const float*)d_in[2];
    const float* Wk = (const float*)d_in[3];
    const float* bk = (const float*)d_in[4];
    const float* Wv = (const float*)d_in[5];
    const float* bv = (const float*)d_in[6];
    const float* Wo = (const float*)d_in[7];
    const float* bo = (const float*)d_in[8];

    unsigned short* xb  = (unsigned short*)d_ws;
    unsigned short* wb  = xb + (size_t)M_ * D_;
    unsigned short* Qb  = wb + (size_t)4 * D_ * D_;
    unsigned short* Kb  = Qb + (size_t)M_ * D_;
    unsigned short* VTb = Kb + (size_t)M_ * D_;
    unsigned short* ctb = VTb + (size_t)M_ * D_;

    int cvt_blocks = (M_ * D_ + 4 * D_ * D_) / 1024;
    cvt_all<<<cvt_blocks, 256, 0, stream>>>(x, Wq, Wk, Wv, Wo, xb, wb);

    qkv_gemm<<<dim3(3 * D_ / 128, M_ / 128), 512, 0, stream>>>(
        xb, wb, bq, bk, bv, Qb, Kb, VTb);

    attn_mfma<<<dim3(B_ * H_, S_ / 256), 512, 0, stream>>>(Qb, Kb, VTb, ctb);

    out_gemm<<<dim3(D_ / 128, M_ / 128), 512, 0, stream>>>(
        ctb, wb + (size_t)3 * D_ * D_, bo, (float*)d_out);
}